// Round 3
// baseline (787.297 us; speedup 1.0000x reference)
//
#include <hip/hip_runtime.h>
#include <hip/hip_fp16.h>
#include <math.h>

#define NN 100000
#define NE 1600000
#define NBKT 391                       // ceil(NN/256) buckets of 256 nodes
#define CHUNK 8192
#define NB1 ((NE + CHUNK - 1) / CHUNK) // 196 blocks
#define HALFN 50000                    // src-range split point (6.4 MB fp16 per phase)

// ---------- phase 0: coarse bucket histogram (LDS-privatized) ----------
__global__ __launch_bounds__(256) void p0_hist_kernel(const int* __restrict__ dst,
                                                      int* __restrict__ bcnt) {
    __shared__ int h[NBKT];
    for (int b = threadIdx.x; b < NBKT; b += 256) h[b] = 0;
    __syncthreads();
    int e0 = blockIdx.x * CHUNK;
    for (int k = 0; k < CHUNK / 256; ++k) {
        int e = e0 + threadIdx.x + k * 256;
        if (e < NE) atomicAdd(&h[dst[e] >> 8], 1);
    }
    __syncthreads();
    for (int b = threadIdx.x; b < NBKT; b += 256)
        if (h[b]) atomicAdd(&bcnt[b], h[b]);
}

// ---------- scan of 391 bucket counts -> base & cursor ----------
__global__ void scan_buckets_kernel(const int* __restrict__ bcnt, int* __restrict__ bbase,
                                    int* __restrict__ bcur) {
    __shared__ int s[512];
    int tid = threadIdx.x;
    int v = (tid < NBKT) ? bcnt[tid] : 0;
    s[tid] = v;
    __syncthreads();
    for (int off = 1; off < 512; off <<= 1) {
        int t = (tid >= off) ? s[tid - off] : 0;
        __syncthreads();
        s[tid] += t;
        __syncthreads();
    }
    if (tid < NBKT) { int ex = s[tid] - v; bbase[tid] = ex; bcur[tid] = ex; }
    if (tid == NBKT) bbase[NBKT] = NE;
}

// ---------- phase 1: scatter packed (src<<8 | dst&255) into bucket runs ----------
__global__ __launch_bounds__(256) void p1_scatter_kernel(const int* __restrict__ src,
                                                         const int* __restrict__ dst,
                                                         int* __restrict__ bcur,
                                                         int* __restrict__ gpair) {
    __shared__ int h[NBKT], rb[NBKT], hc[NBKT];
    int tid = threadIdx.x;
    for (int b = tid; b < NBKT; b += 256) { h[b] = 0; hc[b] = 0; }
    __syncthreads();
    int e0 = blockIdx.x * CHUNK;
    for (int k = 0; k < CHUNK / 256; ++k) {
        int e = e0 + tid + k * 256;
        if (e < NE) atomicAdd(&h[dst[e] >> 8], 1);
    }
    __syncthreads();
    for (int b = tid; b < NBKT; b += 256)
        rb[b] = h[b] ? atomicAdd(&bcur[b], h[b]) : 0;   // reserve block-private run
    __syncthreads();
    for (int k = 0; k < CHUNK / 256; ++k) {
        int e = e0 + tid + k * 256;
        if (e < NE) {
            int d = dst[e], s = src[e];
            int b = d >> 8;
            int pos = rb[b] + atomicAdd(&hc[b], 1);
            gpair[pos] = (s << 8) | (d & 255);
        }
    }
}

// ---------- phase 2: per-bucket place -> csr (src-partitioned), row_start/mid, nrm ----------
// Each node's run: edges with src<HALFN first [row_start,row_mid), then >=HALFN [row_mid,row_end).
__global__ __launch_bounds__(256) void p2_place_kernel(const int* __restrict__ gpair,
                                                       const int* __restrict__ bbase,
                                                       int* __restrict__ csr,
                                                       int* __restrict__ row_start,
                                                       int* __restrict__ row_mid,
                                                       float* __restrict__ nrm) {
    __shared__ int cnt[256], cntLo[256], nexcl[256], baseL[256], baseH[256], pl[256], ph[256];
    int b = blockIdx.x, tid = threadIdx.x;
    int s0 = bbase[b], s1 = bbase[b + 1];
    cnt[tid] = 0; cntLo[tid] = 0; pl[tid] = 0; ph[tid] = 0;
    __syncthreads();
    for (int i = s0 + tid; i < s1; i += 256) {
        int p = gpair[i];
        int l = p & 255;
        atomicAdd(&cnt[l], 1);
        if ((p >> 8) < HALFN) atomicAdd(&cntLo[l], 1);
    }
    __syncthreads();
    int v = cnt[tid];
    nexcl[tid] = v;
    __syncthreads();
    for (int off = 1; off < 256; off <<= 1) {
        int t = (tid >= off) ? nexcl[tid - off] : 0;
        __syncthreads();
        nexcl[tid] += t;
        __syncthreads();
    }
    int ex = nexcl[tid] - v;                 // exclusive within bucket
    int base = s0 + ex;
    int node = (b << 8) + tid;
    if (node < NN) {
        row_start[node] = base;
        row_mid[node]   = base + cntLo[tid];
        nrm[node] = rsqrtf(fmaxf((float)v, 1.0f));
    }
    if (b == NBKT - 1 && tid == 0) row_start[NN] = NE;
    baseL[tid] = base;
    baseH[tid] = base + cntLo[tid];
    __syncthreads();
    for (int i = s0 + tid; i < s1; i += 256) {
        int p = gpair[i];
        int l = p & 255;
        int s = p >> 8;
        int pos = (s < HALFN) ? (baseL[l] + atomicAdd(&pl[l], 1))
                              : (baseH[l] + atomicAdd(&ph[l], 1));
        csr[pos] = s;                        // block-owned contiguous window
    }
}

union H4 { uint2 u; __half2 h[2]; };

// x' = fp16(x * nrm[node]); 4 floats in -> 4 halves (8 B) out per thread
__global__ void scale_x_h_kernel(const float4* __restrict__ x4, const float* __restrict__ nrm,
                                 uint2* __restrict__ xs, int total4) {
    int i = blockIdx.x * blockDim.x + threadIdx.x;
    if (i < total4) {
        float nv = nrm[i >> 4];
        float4 v = x4[i];
        H4 w;
        w.h[0] = __floats2half2_rn(v.x * nv, v.y * nv);
        w.h[1] = __floats2half2_rn(v.z * nv, v.w * nv);
        xs[i] = w.u;
    }
}

// ---------------- gather: one src-range half -> fp16 partial agg ----------------
// part0-proven structure: no LDS, no weights, VGPR ~56, high occupancy.
// Working set = h rows of one half: 6.4 MB (IN=64) / 3.2 MB (IN=32).
// ACC: epilogue reads existing partial and accumulates (in-place RMW; block owns its rows).
template<int IN, bool ACC>
__global__ __launch_bounds__(256) void gcn_gather_kernel(
        const __half* __restrict__ h,
        const int* __restrict__ rs_arr, const int* __restrict__ re_arr,
        const int* __restrict__ csr,
        uint2* __restrict__ pAgg) {
    constexpr int MLP = 8;
    constexpr int RL  = IN / 4;        // lanes per row
    constexpr int EPI = 64 / RL;       // edges per iteration
    int tid = threadIdx.x;
    int wave = tid >> 6, lane = tid & 63;
    int row_slot = lane / RL;
    int f4 = lane % RL;
    int nodeBase = (blockIdx.x * 4 + wave) * MLP;
    const uint2* hp = (const uint2*)h;

    int rsb[MLP], re[MLP];
#pragma unroll
    for (int i = 0; i < MLP; ++i) {
        rsb[i] = rs_arr[nodeBase + i];
        re[i]  = re_arr[nodeBase + i];
    }
    int maxd = 0;
#pragma unroll
    for (int i = 0; i < MLP; ++i) maxd = max(maxd, re[i] - rsb[i]);
#pragma unroll
    for (int i = 0; i < MLP; ++i) rsb[i] += row_slot;

    float4 acc[MLP];
#pragma unroll
    for (int i = 0; i < MLP; ++i) acc[i] = make_float4(0.f, 0.f, 0.f, 0.f);

    for (int t = 0; t < maxd; t += EPI) {
        int s[MLP]; float m[MLP];
#pragma unroll
        for (int i = 0; i < MLP; ++i) {                 // batch: all csr loads
            int jj = rsb[i] + t;
            bool ok = jj < re[i];
            s[i] = csr[ok ? jj : 0];
            m[i] = ok ? 1.f : 0.f;
        }
        H4 v[MLP];
#pragma unroll
        for (int i = 0; i < MLP; ++i)                   // batch: all row loads
            v[i].u = hp[(size_t)s[i] * RL + f4];
#pragma unroll
        for (int i = 0; i < MLP; ++i) {                 // math
            float2 f01 = __half22float2(v[i].h[0]);
            float2 f23 = __half22float2(v[i].h[1]);
            acc[i].x = fmaf(m[i], f01.x, acc[i].x);
            acc[i].y = fmaf(m[i], f01.y, acc[i].y);
            acc[i].z = fmaf(m[i], f23.x, acc[i].z);
            acc[i].w = fmaf(m[i], f23.y, acc[i].w);
        }
    }

#pragma unroll
    for (int i = 0; i < MLP; ++i) {
        for (int o = RL; o < 64; o <<= 1) {
            acc[i].x += __shfl_xor(acc[i].x, o);
            acc[i].y += __shfl_xor(acc[i].y, o);
            acc[i].z += __shfl_xor(acc[i].z, o);
            acc[i].w += __shfl_xor(acc[i].w, o);
        }
    }

    if (row_slot == 0) {
        if (ACC) {
            uint2 old[MLP];
#pragma unroll
            for (int i = 0; i < MLP; ++i)               // batch the partial reads
                old[i] = pAgg[(size_t)(nodeBase + i) * RL + f4];
#pragma unroll
            for (int i = 0; i < MLP; ++i) {
                H4 o4; o4.u = old[i];
                float2 a01 = __half22float2(o4.h[0]);
                float2 a23 = __half22float2(o4.h[1]);
                acc[i].x += a01.x; acc[i].y += a01.y;
                acc[i].z += a23.x; acc[i].w += a23.y;
            }
        }
#pragma unroll
        for (int i = 0; i < MLP; ++i) {
            H4 w;
            w.h[0] = __floats2half2_rn(acc[i].x, acc[i].y);
            w.h[1] = __floats2half2_rn(acc[i].z, acc[i].w);
            pAgg[(size_t)(nodeBase + i) * RL + f4] = w.u;
        }
    }
}

// ---------------- apply: partial agg -> linear + act (zero-LDS GEMV) ----------------
// R2 post-mortem: LDS-GEMV was LDS-pipe-bound (~2x512 ds_read/thread, 1 pipe/CU vs 4 SIMDs).
// v3: W column in VGPRs (lane o holds W[o][*]); agg row via broadcast global loads
// (all lanes same addr -> one L1 transaction). Inner loop is pure VALU.
// out = act(nrm_dst*(agg@W^T)+b); SCALE => *nrm_dst, fp16 out.
// DUAL: mu|lv fp32 heads + fused z' = fp16((eps*exp(0.5 lv)+mu)*nrm) -> zbuf.
template<int IN, int ACT, bool SCALE, bool DUAL>
__global__ __launch_bounds__(256) void gcn_apply_kernel(
        const __half* __restrict__ pAgg,
        const float* __restrict__ nrm,
        const float* __restrict__ Wa, const float* __restrict__ ba,
        const float* __restrict__ Wb, const float* __restrict__ bb,
        void* __restrict__ outv, float* __restrict__ out2,
        const float* __restrict__ eps, __half* __restrict__ zbuf) {
    constexpr int MLP = 8;
    constexpr int Q = IN / 4;          // uint2 (4-half) chunks per agg row
    int tid = threadIdx.x;
    int wave = tid >> 6, lane = tid & 63;
    int nodeBase = (blockIdx.x * 4 + wave) * MLP;

    // per-lane W column: out_o = sum_k agg_k * W[o][k]; lane owns o.
    float wcol[IN];
    float bias;
    if (DUAL) {
        const float* Wrow = (lane < 32) ? (Wa + (size_t)lane * 64)
                                        : (Wb + (size_t)(lane - 32) * 64);
#pragma unroll
        for (int k = 0; k < IN; k += 4) {
            float4 w4 = *(const float4*)(Wrow + k);
            wcol[k] = w4.x; wcol[k + 1] = w4.y; wcol[k + 2] = w4.z; wcol[k + 3] = w4.w;
        }
        bias = (lane < 32) ? ba[lane] : bb[lane - 32];
    } else {
        const float* Wrow = Wa + (size_t)lane * IN;
#pragma unroll
        for (int k = 0; k < IN; k += 4) {
            float4 w4 = *(const float4*)(Wrow + k);
            wcol[k] = w4.x; wcol[k + 1] = w4.y; wcol[k + 2] = w4.z; wcol[k + 3] = w4.w;
        }
        bias = ba[lane];
    }
    const uint2* ap = (const uint2*)pAgg;

#pragma unroll
    for (int i = 0; i < MLP; ++i) {
        int node = nodeBase + i;
        uint2 a[Q];
#pragma unroll
        for (int q = 0; q < Q; ++q)                     // broadcast loads (same addr/wave)
            a[q] = ap[(size_t)node * Q + q];
        float oa = 0.f;
#pragma unroll
        for (int q = 0; q < Q; ++q) {
            H4 v; v.u = a[q];
            float2 f01 = __half22float2(v.h[0]);
            float2 f23 = __half22float2(v.h[1]);
            oa = fmaf(f01.x, wcol[4 * q],     oa);
            oa = fmaf(f01.y, wcol[4 * q + 1], oa);
            oa = fmaf(f23.x, wcol[4 * q + 2], oa);
            oa = fmaf(f23.y, wcol[4 * q + 3], oa);
        }
        float nv = nrm[node];
        oa = oa * nv + bias;
        if (ACT == 1) oa = fmaxf(oa, 0.f);
        if (ACT == 2) oa = 1.f / (1.f + expf(-oa));

        if (DUAL) {
            float* mu_p = (float*)outv;
            if (lane < 32) mu_p[(size_t)node * 32 + lane]        = oa;
            else           out2[(size_t)node * 32 + (lane - 32)] = oa;
            float lv_v = __shfl(oa, (lane + 32) & 63);   // lanes<32 receive lv
            if (lane < 32) {
                float e = eps[(size_t)node * 32 + lane];
                zbuf[(size_t)node * 32 + lane] = __float2half((e * expf(0.5f * lv_v) + oa) * nv);
            }
        } else if (SCALE) {
            ((__half*)outv)[(size_t)node * 64 + lane] = __float2half(oa * nv);
        } else {
            ((float*)outv)[(size_t)node * 64 + lane] = oa;
        }
    }
}

extern "C" void kernel_launch(void* const* d_in, const int* in_sizes, int n_in,
                              void* d_out, int out_size, void* d_ws, size_t ws_size,
                              hipStream_t stream) {
    const float* x    = (const float*)d_in[0];
    const int*   esrc = (const int*)d_in[1];
    const int*   edst = (const int*)d_in[2];
    const float* eps  = (const float*)d_in[3];
    const float* W1  = (const float*)d_in[4];  const float* b1  = (const float*)d_in[5];
    const float* W2  = (const float*)d_in[6];  const float* b2  = (const float*)d_in[7];
    const float* W31 = (const float*)d_in[8];  const float* b31 = (const float*)d_in[9];
    const float* W32 = (const float*)d_in[10]; const float* b32 = (const float*)d_in[11];
    const float* W4  = (const float*)d_in[12]; const float* b4  = (const float*)d_in[13];
    const float* W5  = (const float*)d_in[14]; const float* b5  = (const float*)d_in[15];
    const float* W6  = (const float*)d_in[16]; const float* b6  = (const float*)d_in[17];

    float* outp  = (float*)d_out;
    float* recon = outp;                        // N*64
    float* mu    = outp + (size_t)NN * 64;      // N*32
    float* lv    = mu   + (size_t)NN * 32;      // N*32

    int* wsI       = (int*)d_ws;
    int* bcnt      = wsI;                       // 392
    int* bbase     = bcnt + 392;                // 392
    int* bcur      = bbase + 392;               // 392
    int* row_start = bcur + 392;                // NN+1, pad to NN+4
    int* row_mid   = row_start + NN + 4;        // NN, pad to NN+4
    int* csr       = row_mid + NN + 4;          // NE
    float* nrm     = (float*)(csr + NE);        // NN
    __half* pAgg   = (__half*)(nrm + NN);       // NN*64 halves (12.8 MB), 16B-aligned
    __half* hA     = pAgg + (size_t)NN * 64;    // NN*64 halves
    __half* hB     = hA + (size_t)NN * 64;      // NN*64 halves
    int* gpair     = (int*)pAgg;                // aliased: dead after p2_place

    const int SB = 256;
    const int fgrid = NN / 32;                  // 3125: 4 waves x 8 nodes

    // ---- CSR build: bucket counting sort (src-partitioned per node) ----
    hipMemsetAsync(bcnt, 0, 392 * sizeof(int), stream);
    p0_hist_kernel<<<NB1, 256, 0, stream>>>(edst, bcnt);
    scan_buckets_kernel<<<1, 512, 0, stream>>>(bcnt, bbase, bcur);
    p1_scatter_kernel<<<NB1, 256, 0, stream>>>(esrc, edst, bcur, gpair);
    p2_place_kernel<<<NBKT, 256, 0, stream>>>(gpair, bbase, csr, row_start, row_mid, nrm);

    // ---- pre-scale input to fp16 ----
    scale_x_h_kernel<<<(NN * 16 + SB - 1) / SB, SB, 0, stream>>>((const float4*)x, nrm, (uint2*)hA, NN * 16);

    uint2* pW = (uint2*)pAgg;
    const __half* pH = (const __half*)pAgg;
    const int* rm = row_mid;
    const int* rsA = row_start;
    const int* reA = row_start + 1;

    // ---- layers: gather_lo + gather_hi(ACC) + apply (zero-LDS) ----
    // L1
    gcn_gather_kernel<64, false><<<fgrid, 256, 0, stream>>>(hA, rsA, rm, csr, pW);
    gcn_gather_kernel<64, true ><<<fgrid, 256, 0, stream>>>(hA, rm, reA, csr, pW);
    gcn_apply_kernel<64, 1, true,  false><<<fgrid, 256, 0, stream>>>(pH, nrm, W1,  b1,  nullptr, nullptr, hB,    nullptr, nullptr, nullptr);
    // L2
    gcn_gather_kernel<64, false><<<fgrid, 256, 0, stream>>>(hB, rsA, rm, csr, pW);
    gcn_gather_kernel<64, true ><<<fgrid, 256, 0, stream>>>(hB, rm, reA, csr, pW);
    gcn_apply_kernel<64, 1, true,  false><<<fgrid, 256, 0, stream>>>(pH, nrm, W2,  b2,  nullptr, nullptr, hA,    nullptr, nullptr, nullptr);
    // L3 dual: mu/lv -> d_out (fp32), fused z' -> hB (fp16, N*32)
    gcn_gather_kernel<64, false><<<fgrid, 256, 0, stream>>>(hA, rsA, rm, csr, pW);
    gcn_gather_kernel<64, true ><<<fgrid, 256, 0, stream>>>(hA, rm, reA, csr, pW);
    gcn_apply_kernel<64, 0, false, true ><<<fgrid, 256, 0, stream>>>(pH, nrm, W31, b31, W32,     b32,     mu,    lv,      eps,     hB);
    // L4 (IN=32)
    gcn_gather_kernel<32, false><<<fgrid, 256, 0, stream>>>(hB, rsA, rm, csr, pW);
    gcn_gather_kernel<32, true ><<<fgrid, 256, 0, stream>>>(hB, rm, reA, csr, pW);
    gcn_apply_kernel<32, 1, true,  false><<<fgrid, 256, 0, stream>>>(pH, nrm, W4,  b4,  nullptr, nullptr, hA,    nullptr, nullptr, nullptr);
    // L5
    gcn_gather_kernel<64, false><<<fgrid, 256, 0, stream>>>(hA, rsA, rm, csr, pW);
    gcn_gather_kernel<64, true ><<<fgrid, 256, 0, stream>>>(hA, rm, reA, csr, pW);
    gcn_apply_kernel<64, 1, true,  false><<<fgrid, 256, 0, stream>>>(pH, nrm, W5,  b5,  nullptr, nullptr, hB,    nullptr, nullptr, nullptr);
    // L6
    gcn_gather_kernel<64, false><<<fgrid, 256, 0, stream>>>(hB, rsA, rm, csr, pW);
    gcn_gather_kernel<64, true ><<<fgrid, 256, 0, stream>>>(hB, rm, reA, csr, pW);
    gcn_apply_kernel<64, 2, false, false><<<fgrid, 256, 0, stream>>>(pH, nrm, W6,  b6,  nullptr, nullptr, recon, nullptr, nullptr, nullptr);
}

// Round 4
// 577.372 us; speedup vs baseline: 1.3636x; 1.3636x over previous
//
#include <hip/hip_runtime.h>
#include <hip/hip_fp16.h>
#include <math.h>

#define NN 100000
#define NE 1600000
#define NBKT 391                       // ceil(NN/256) buckets of 256 nodes
#define CHUNK 8192
#define NB1 ((NE + CHUNK - 1) / CHUNK) // 196 blocks
#define HALFN 50000                    // src-range split point (6.4 MB fp16 per phase)

typedef _Float16 v8h __attribute__((ext_vector_type(8)));
typedef float v4f __attribute__((ext_vector_type(4)));

// ---------- phase 0: coarse bucket histogram (LDS-privatized) ----------
__global__ __launch_bounds__(256) void p0_hist_kernel(const int* __restrict__ dst,
                                                      int* __restrict__ bcnt) {
    __shared__ int h[NBKT];
    for (int b = threadIdx.x; b < NBKT; b += 256) h[b] = 0;
    __syncthreads();
    int e0 = blockIdx.x * CHUNK;
    for (int k = 0; k < CHUNK / 256; ++k) {
        int e = e0 + threadIdx.x + k * 256;
        if (e < NE) atomicAdd(&h[dst[e] >> 8], 1);
    }
    __syncthreads();
    for (int b = threadIdx.x; b < NBKT; b += 256)
        if (h[b]) atomicAdd(&bcnt[b], h[b]);
}

// ---------- scan of 391 bucket counts -> base & cursor ----------
__global__ void scan_buckets_kernel(const int* __restrict__ bcnt, int* __restrict__ bbase,
                                    int* __restrict__ bcur) {
    __shared__ int s[512];
    int tid = threadIdx.x;
    int v = (tid < NBKT) ? bcnt[tid] : 0;
    s[tid] = v;
    __syncthreads();
    for (int off = 1; off < 512; off <<= 1) {
        int t = (tid >= off) ? s[tid - off] : 0;
        __syncthreads();
        s[tid] += t;
        __syncthreads();
    }
    if (tid < NBKT) { int ex = s[tid] - v; bbase[tid] = ex; bcur[tid] = ex; }
    if (tid == NBKT) bbase[NBKT] = NE;
}

// ---------- phase 1: scatter packed (src<<8 | dst&255) into bucket runs ----------
__global__ __launch_bounds__(256) void p1_scatter_kernel(const int* __restrict__ src,
                                                         const int* __restrict__ dst,
                                                         int* __restrict__ bcur,
                                                         int* __restrict__ gpair) {
    __shared__ int h[NBKT], rb[NBKT], hc[NBKT];
    int tid = threadIdx.x;
    for (int b = tid; b < NBKT; b += 256) { h[b] = 0; hc[b] = 0; }
    __syncthreads();
    int e0 = blockIdx.x * CHUNK;
    for (int k = 0; k < CHUNK / 256; ++k) {
        int e = e0 + tid + k * 256;
        if (e < NE) atomicAdd(&h[dst[e] >> 8], 1);
    }
    __syncthreads();
    for (int b = tid; b < NBKT; b += 256)
        rb[b] = h[b] ? atomicAdd(&bcur[b], h[b]) : 0;   // reserve block-private run
    __syncthreads();
    for (int k = 0; k < CHUNK / 256; ++k) {
        int e = e0 + tid + k * 256;
        if (e < NE) {
            int d = dst[e], s = src[e];
            int b = d >> 8;
            int pos = rb[b] + atomicAdd(&hc[b], 1);
            gpair[pos] = (s << 8) | (d & 255);
        }
    }
}

// ---------- phase 2: per-bucket place -> csr (src-partitioned), row_start/mid, nrm ----------
// Each node's run: edges with src<HALFN first [row_start,row_mid), then >=HALFN [row_mid,row_end).
__global__ __launch_bounds__(256) void p2_place_kernel(const int* __restrict__ gpair,
                                                       const int* __restrict__ bbase,
                                                       int* __restrict__ csr,
                                                       int* __restrict__ row_start,
                                                       int* __restrict__ row_mid,
                                                       float* __restrict__ nrm) {
    __shared__ int cnt[256], cntLo[256], nexcl[256], baseL[256], baseH[256], pl[256], ph[256];
    int b = blockIdx.x, tid = threadIdx.x;
    int s0 = bbase[b], s1 = bbase[b + 1];
    cnt[tid] = 0; cntLo[tid] = 0; pl[tid] = 0; ph[tid] = 0;
    __syncthreads();
    for (int i = s0 + tid; i < s1; i += 256) {
        int p = gpair[i];
        int l = p & 255;
        atomicAdd(&cnt[l], 1);
        if ((p >> 8) < HALFN) atomicAdd(&cntLo[l], 1);
    }
    __syncthreads();
    int v = cnt[tid];
    nexcl[tid] = v;
    __syncthreads();
    for (int off = 1; off < 256; off <<= 1) {
        int t = (tid >= off) ? nexcl[tid - off] : 0;
        __syncthreads();
        nexcl[tid] += t;
        __syncthreads();
    }
    int ex = nexcl[tid] - v;                 // exclusive within bucket
    int base = s0 + ex;
    int node = (b << 8) + tid;
    if (node < NN) {
        row_start[node] = base;
        row_mid[node]   = base + cntLo[tid];
        nrm[node] = rsqrtf(fmaxf((float)v, 1.0f));
    }
    if (b == NBKT - 1 && tid == 0) row_start[NN] = NE;
    baseL[tid] = base;
    baseH[tid] = base + cntLo[tid];
    __syncthreads();
    for (int i = s0 + tid; i < s1; i += 256) {
        int p = gpair[i];
        int l = p & 255;
        int s = p >> 8;
        int pos = (s < HALFN) ? (baseL[l] + atomicAdd(&pl[l], 1))
                              : (baseH[l] + atomicAdd(&ph[l], 1));
        csr[pos] = s;                        // block-owned contiguous window
    }
}

union H4 { uint2 u; __half2 h[2]; };

// x' = fp16(x * nrm[node]); 4 floats in -> 4 halves (8 B) out per thread
__global__ void scale_x_h_kernel(const float4* __restrict__ x4, const float* __restrict__ nrm,
                                 uint2* __restrict__ xs, int total4) {
    int i = blockIdx.x * blockDim.x + threadIdx.x;
    if (i < total4) {
        float nv = nrm[i >> 4];
        float4 v = x4[i];
        H4 w;
        w.h[0] = __floats2half2_rn(v.x * nv, v.y * nv);
        w.h[1] = __floats2half2_rn(v.z * nv, v.w * nv);
        xs[i] = w.u;
    }
}

// ---------------- gather: one src-range half -> fp16 partial agg ----------------
// part0-proven structure: no LDS, no weights, VGPR ~56, high occupancy.
// Working set = h rows of one half: 6.4 MB (IN=64) / 3.2 MB (IN=32).
// ACC: epilogue reads existing partial and accumulates (in-place RMW; block owns its rows).
template<int IN, bool ACC>
__global__ __launch_bounds__(256) void gcn_gather_kernel(
        const __half* __restrict__ h,
        const int* __restrict__ rs_arr, const int* __restrict__ re_arr,
        const int* __restrict__ csr,
        uint2* __restrict__ pAgg) {
    constexpr int MLP = 8;
    constexpr int RL  = IN / 4;        // lanes per row
    constexpr int EPI = 64 / RL;       // edges per iteration
    int tid = threadIdx.x;
    int wave = tid >> 6, lane = tid & 63;
    int row_slot = lane / RL;
    int f4 = lane % RL;
    int nodeBase = (blockIdx.x * 4 + wave) * MLP;
    const uint2* hp = (const uint2*)h;

    int rsb[MLP], re[MLP];
#pragma unroll
    for (int i = 0; i < MLP; ++i) {
        rsb[i] = rs_arr[nodeBase + i];
        re[i]  = re_arr[nodeBase + i];
    }
    int maxd = 0;
#pragma unroll
    for (int i = 0; i < MLP; ++i) maxd = max(maxd, re[i] - rsb[i]);
#pragma unroll
    for (int i = 0; i < MLP; ++i) rsb[i] += row_slot;

    float4 acc[MLP];
#pragma unroll
    for (int i = 0; i < MLP; ++i) acc[i] = make_float4(0.f, 0.f, 0.f, 0.f);

    for (int t = 0; t < maxd; t += EPI) {
        int s[MLP]; float m[MLP];
#pragma unroll
        for (int i = 0; i < MLP; ++i) {                 // batch: all csr loads
            int jj = rsb[i] + t;
            bool ok = jj < re[i];
            s[i] = csr[ok ? jj : 0];
            m[i] = ok ? 1.f : 0.f;
        }
        H4 v[MLP];
#pragma unroll
        for (int i = 0; i < MLP; ++i)                   // batch: all row loads
            v[i].u = hp[(size_t)s[i] * RL + f4];
#pragma unroll
        for (int i = 0; i < MLP; ++i) {                 // math
            float2 f01 = __half22float2(v[i].h[0]);
            float2 f23 = __half22float2(v[i].h[1]);
            acc[i].x = fmaf(m[i], f01.x, acc[i].x);
            acc[i].y = fmaf(m[i], f01.y, acc[i].y);
            acc[i].z = fmaf(m[i], f23.x, acc[i].z);
            acc[i].w = fmaf(m[i], f23.y, acc[i].w);
        }
    }

#pragma unroll
    for (int i = 0; i < MLP; ++i) {
        for (int o = RL; o < 64; o <<= 1) {
            acc[i].x += __shfl_xor(acc[i].x, o);
            acc[i].y += __shfl_xor(acc[i].y, o);
            acc[i].z += __shfl_xor(acc[i].z, o);
            acc[i].w += __shfl_xor(acc[i].w, o);
        }
    }

    if (row_slot == 0) {
        if (ACC) {
            uint2 old[MLP];
#pragma unroll
            for (int i = 0; i < MLP; ++i)               // batch the partial reads
                old[i] = pAgg[(size_t)(nodeBase + i) * RL + f4];
#pragma unroll
            for (int i = 0; i < MLP; ++i) {
                H4 o4; o4.u = old[i];
                float2 a01 = __half22float2(o4.h[0]);
                float2 a23 = __half22float2(o4.h[1]);
                acc[i].x += a01.x; acc[i].y += a01.y;
                acc[i].z += a23.x; acc[i].w += a23.y;
            }
        }
#pragma unroll
        for (int i = 0; i < MLP; ++i) {
            H4 w;
            w.h[0] = __floats2half2_rn(acc[i].x, acc[i].y);
            w.h[1] = __floats2half2_rn(acc[i].z, acc[i].w);
            pAgg[(size_t)(nodeBase + i) * RL + f4] = w.u;
        }
    }
}

// ---------------- apply: MFMA GEMM  out = act(nrm*(agg @ W^T) + b) ----------------
// R3 post-mortem: hand-rolled GEMV was latency/LDS-bound. apply IS a 100k x 64 x 64 GEMM
// -> matrix cores (Guideline 10). W split hi/lo fp16 (two MFMA accums) => effective ~fp32
// weights, no precision regression vs fp32-W GEMV. agg stays fp16 (unchanged).
// Layouts (m89-verified): A row=lane&15, k=(lane>>4)*8+j ; B col=lane&15, k=(lane>>4)*8+j ;
// C/D col=lane&15, row=(lane>>4)*4+reg.
// Per block: 4 waves x 32 nodes = 128 nodes. Per wave: 2 A-tiles(16) x 4 out-tiles(16).
template<int IN, int ACT, bool SCALE, bool DUAL>
__global__ __launch_bounds__(256) void gcn_apply_mfma_kernel(
        const __half* __restrict__ pAgg,
        const float* __restrict__ nrm,
        const float* __restrict__ Wa, const float* __restrict__ ba,
        const float* __restrict__ Wb, const float* __restrict__ bb,
        void* __restrict__ outv, float* __restrict__ out2,
        const float* __restrict__ eps, __half* __restrict__ zbuf) {
    constexpr int KH = IN / 32;                 // K halves of 32 (2 for IN=64, 1 for IN=32)
    int tid = threadIdx.x;
    int wave = tid >> 6, lane = tid & 63;
    int col = lane & 15, kgrp = lane >> 4;

    // B fragments: B[k][c] = W[o = t*16+col][k]; hi/lo fp16 split of fp32 W.
    v8h Bhi[4][KH], Blo[4][KH];
    float bias[4];
#pragma unroll
    for (int t = 0; t < 4; ++t) {
        const float* wrow;
        if (DUAL) wrow = (t < 2) ? (Wa + (size_t)(t * 16 + col) * 64)
                                 : (Wb + (size_t)((t - 2) * 16 + col) * 64);
        else      wrow = Wa + (size_t)(t * 16 + col) * IN;
        bias[t] = DUAL ? ((t < 2) ? ba[t * 16 + col] : bb[(t - 2) * 16 + col])
                       : ba[t * 16 + col];
#pragma unroll
        for (int kh = 0; kh < KH; ++kh) {
            const float* wp = wrow + kh * 32 + kgrp * 8;
            float4 w0 = *(const float4*)(wp);
            float4 w1 = *(const float4*)(wp + 4);
            float wv[8] = {w0.x, w0.y, w0.z, w0.w, w1.x, w1.y, w1.z, w1.w};
#pragma unroll
            for (int j = 0; j < 8; ++j) {
                _Float16 hv = (_Float16)wv[j];
                Bhi[t][kh][j] = hv;
                Blo[t][kh][j] = (_Float16)(wv[j] - (float)hv);
            }
        }
    }

    int base = blockIdx.x * 128 + wave * 32;
    const _Float16* ag = (const _Float16*)pAgg;
    v4f acc[2][4];
#pragma unroll
    for (int a2 = 0; a2 < 2; ++a2)
#pragma unroll
        for (int t = 0; t < 4; ++t)
            acc[a2][t] = (v4f){0.f, 0.f, 0.f, 0.f};

#pragma unroll
    for (int a2 = 0; a2 < 2; ++a2) {
        int arow = base + a2 * 16 + col;
        if (arow > NN - 1) arow = NN - 1;               // tail guard (stores masked below)
        const _Float16* arp = ag + (size_t)arow * IN + kgrp * 8;
        v8h A0 = *(const v8h*)(arp);
        v8h A1{};
        if constexpr (KH == 2) A1 = *(const v8h*)(arp + 32);
#pragma unroll
        for (int t = 0; t < 4; ++t) {
            acc[a2][t] = __builtin_amdgcn_mfma_f32_16x16x32_f16(A0, Bhi[t][0], acc[a2][t], 0, 0, 0);
            acc[a2][t] = __builtin_amdgcn_mfma_f32_16x16x32_f16(A0, Blo[t][0], acc[a2][t], 0, 0, 0);
            if constexpr (KH == 2) {
                acc[a2][t] = __builtin_amdgcn_mfma_f32_16x16x32_f16(A1, Bhi[t][1], acc[a2][t], 0, 0, 0);
                acc[a2][t] = __builtin_amdgcn_mfma_f32_16x16x32_f16(A1, Blo[t][1], acc[a2][t], 0, 0, 0);
            }
        }
    }

    // epilogue: node = base + a2*16 + kgrp*4 + r ; o = t*16 + col
#pragma unroll
    for (int a2 = 0; a2 < 2; ++a2) {
#pragma unroll
        for (int r = 0; r < 4; ++r) {
            int node = base + a2 * 16 + kgrp * 4 + r;
            if (node >= NN) continue;
            float nv = nrm[node];
            float oa[4];
#pragma unroll
            for (int t = 0; t < 4; ++t) {
                float v = acc[a2][t][r] * nv + bias[t];
                if (ACT == 1) v = fmaxf(v, 0.f);
                if (ACT == 2) v = 1.f / (1.f + expf(-v));
                oa[t] = v;
            }
            if (DUAL) {
                float* mu_p = (float*)outv;
#pragma unroll
                for (int t = 0; t < 2; ++t) {
                    int zo = t * 16 + col;
                    float muv = oa[t], lvv = oa[t + 2];
                    mu_p[(size_t)node * 32 + zo] = muv;
                    out2[(size_t)node * 32 + zo] = lvv;
                    float e = eps[(size_t)node * 32 + zo];
                    zbuf[(size_t)node * 32 + zo] = __float2half((e * expf(0.5f * lvv) + muv) * nv);
                }
            } else if (SCALE) {
                __half* op = (__half*)outv + (size_t)node * 64 + col;
#pragma unroll
                for (int t = 0; t < 4; ++t) op[t * 16] = __float2half(oa[t] * nv);
            } else {
                float* op = (float*)outv + (size_t)node * 64 + col;
#pragma unroll
                for (int t = 0; t < 4; ++t) op[t * 16] = oa[t];
            }
        }
    }
}

extern "C" void kernel_launch(void* const* d_in, const int* in_sizes, int n_in,
                              void* d_out, int out_size, void* d_ws, size_t ws_size,
                              hipStream_t stream) {
    const float* x    = (const float*)d_in[0];
    const int*   esrc = (const int*)d_in[1];
    const int*   edst = (const int*)d_in[2];
    const float* eps  = (const float*)d_in[3];
    const float* W1  = (const float*)d_in[4];  const float* b1  = (const float*)d_in[5];
    const float* W2  = (const float*)d_in[6];  const float* b2  = (const float*)d_in[7];
    const float* W31 = (const float*)d_in[8];  const float* b31 = (const float*)d_in[9];
    const float* W32 = (const float*)d_in[10]; const float* b32 = (const float*)d_in[11];
    const float* W4  = (const float*)d_in[12]; const float* b4  = (const float*)d_in[13];
    const float* W5  = (const float*)d_in[14]; const float* b5  = (const float*)d_in[15];
    const float* W6  = (const float*)d_in[16]; const float* b6  = (const float*)d_in[17];

    float* outp  = (float*)d_out;
    float* recon = outp;                        // N*64
    float* mu    = outp + (size_t)NN * 64;      // N*32
    float* lv    = mu   + (size_t)NN * 32;      // N*32

    int* wsI       = (int*)d_ws;
    int* bcnt      = wsI;                       // 392
    int* bbase     = bcnt + 392;                // 392
    int* bcur      = bbase + 392;               // 392
    int* row_start = bcur + 392;                // NN+1, pad to NN+4
    int* row_mid   = row_start + NN + 4;        // NN, pad to NN+4
    int* csr       = row_mid + NN + 4;          // NE
    float* nrm     = (float*)(csr + NE);        // NN
    __half* pAgg   = (__half*)(nrm + NN);       // NN*64 halves (12.8 MB), 16B-aligned
    __half* hA     = pAgg + (size_t)NN * 64;    // NN*64 halves
    __half* hB     = hA + (size_t)NN * 64;      // NN*64 halves
    int* gpair     = (int*)pAgg;                // aliased: dead after p2_place

    const int SB = 256;
    const int fgrid = NN / 32;                  // 3125: 4 waves x 8 nodes
    const int agrid = (NN + 127) / 128;         // 782: MFMA apply, 128 nodes/block

    // ---- CSR build: bucket counting sort (src-partitioned per node) ----
    hipMemsetAsync(bcnt, 0, 392 * sizeof(int), stream);
    p0_hist_kernel<<<NB1, 256, 0, stream>>>(edst, bcnt);
    scan_buckets_kernel<<<1, 512, 0, stream>>>(bcnt, bbase, bcur);
    p1_scatter_kernel<<<NB1, 256, 0, stream>>>(esrc, edst, bcur, gpair);
    p2_place_kernel<<<NBKT, 256, 0, stream>>>(gpair, bbase, csr, row_start, row_mid, nrm);

    // ---- pre-scale input to fp16 ----
    scale_x_h_kernel<<<(NN * 16 + SB - 1) / SB, SB, 0, stream>>>((const float4*)x, nrm, (uint2*)hA, NN * 16);

    uint2* pW = (uint2*)pAgg;
    const __half* pH = (const __half*)pAgg;
    const int* rm = row_mid;
    const int* rsA = row_start;
    const int* reA = row_start + 1;

    // ---- layers: gather_lo + gather_hi(ACC) + apply (MFMA) ----
    // L1
    gcn_gather_kernel<64, false><<<fgrid, 256, 0, stream>>>(hA, rsA, rm, csr, pW);
    gcn_gather_kernel<64, true ><<<fgrid, 256, 0, stream>>>(hA, rm, reA, csr, pW);
    gcn_apply_mfma_kernel<64, 1, true,  false><<<agrid, 256, 0, stream>>>(pH, nrm, W1,  b1,  nullptr, nullptr, hB,    nullptr, nullptr, nullptr);
    // L2
    gcn_gather_kernel<64, false><<<fgrid, 256, 0, stream>>>(hB, rsA, rm, csr, pW);
    gcn_gather_kernel<64, true ><<<fgrid, 256, 0, stream>>>(hB, rm, reA, csr, pW);
    gcn_apply_mfma_kernel<64, 1, true,  false><<<agrid, 256, 0, stream>>>(pH, nrm, W2,  b2,  nullptr, nullptr, hA,    nullptr, nullptr, nullptr);
    // L3 dual: mu/lv -> d_out (fp32), fused z' -> hB (fp16, N*32)
    gcn_gather_kernel<64, false><<<fgrid, 256, 0, stream>>>(hA, rsA, rm, csr, pW);
    gcn_gather_kernel<64, true ><<<fgrid, 256, 0, stream>>>(hA, rm, reA, csr, pW);
    gcn_apply_mfma_kernel<64, 0, false, true ><<<agrid, 256, 0, stream>>>(pH, nrm, W31, b31, W32,     b32,     mu,    lv,      eps,     hB);
    // L4 (IN=32)
    gcn_gather_kernel<32, false><<<fgrid, 256, 0, stream>>>(hB, rsA, rm, csr, pW);
    gcn_gather_kernel<32, true ><<<fgrid, 256, 0, stream>>>(hB, rm, reA, csr, pW);
    gcn_apply_mfma_kernel<32, 1, true,  false><<<agrid, 256, 0, stream>>>(pH, nrm, W4,  b4,  nullptr, nullptr, hA,    nullptr, nullptr, nullptr);
    // L5
    gcn_gather_kernel<64, false><<<fgrid, 256, 0, stream>>>(hA, rsA, rm, csr, pW);
    gcn_gather_kernel<64, true ><<<fgrid, 256, 0, stream>>>(hA, rm, reA, csr, pW);
    gcn_apply_mfma_kernel<64, 1, true,  false><<<agrid, 256, 0, stream>>>(pH, nrm, W5,  b5,  nullptr, nullptr, hB,    nullptr, nullptr, nullptr);
    // L6
    gcn_gather_kernel<64, false><<<fgrid, 256, 0, stream>>>(hB, rsA, rm, csr, pW);
    gcn_gather_kernel<64, true ><<<fgrid, 256, 0, stream>>>(hB, rm, reA, csr, pW);
    gcn_apply_mfma_kernel<64, 2, false, false><<<agrid, 256, 0, stream>>>(pH, nrm, W6,  b6,  nullptr, nullptr, recon, nullptr, nullptr, nullptr);
}

// Round 5
// 553.137 us; speedup vs baseline: 1.4233x; 1.0438x over previous
//
#include <hip/hip_runtime.h>
#include <hip/hip_fp16.h>
#include <math.h>

#define NN 100000
#define NE 1600000
#define NBKT 391                       // ceil(NN/256) buckets of 256 nodes
#define CHUNK 8192
#define NB1 ((NE + CHUNK - 1) / CHUNK) // 196 blocks
#define QSEG 25000                     // src-quartile width: 4 slices x 3.2 MB fp16
#define NNP (NN + 8)                   // padded stride for seg arrays

typedef _Float16 v8h __attribute__((ext_vector_type(8)));
typedef float v4f __attribute__((ext_vector_type(4)));

// ---------- phase 0: coarse bucket histogram (LDS-privatized) ----------
__global__ __launch_bounds__(256) void p0_hist_kernel(const int* __restrict__ dst,
                                                      int* __restrict__ bcnt) {
    __shared__ int h[NBKT];
    for (int b = threadIdx.x; b < NBKT; b += 256) h[b] = 0;
    __syncthreads();
    int e0 = blockIdx.x * CHUNK;
    for (int k = 0; k < CHUNK / 256; ++k) {
        int e = e0 + threadIdx.x + k * 256;
        if (e < NE) atomicAdd(&h[dst[e] >> 8], 1);
    }
    __syncthreads();
    for (int b = threadIdx.x; b < NBKT; b += 256)
        if (h[b]) atomicAdd(&bcnt[b], h[b]);
}

// ---------- scan of 391 bucket counts -> base & cursor ----------
__global__ void scan_buckets_kernel(const int* __restrict__ bcnt, int* __restrict__ bbase,
                                    int* __restrict__ bcur) {
    __shared__ int s[512];
    int tid = threadIdx.x;
    int v = (tid < NBKT) ? bcnt[tid] : 0;
    s[tid] = v;
    __syncthreads();
    for (int off = 1; off < 512; off <<= 1) {
        int t = (tid >= off) ? s[tid - off] : 0;
        __syncthreads();
        s[tid] += t;
        __syncthreads();
    }
    if (tid < NBKT) { int ex = s[tid] - v; bbase[tid] = ex; bcur[tid] = ex; }
    if (tid == NBKT) bbase[NBKT] = NE;
}

// ---------- phase 1: scatter packed (src<<8 | dst&255) into bucket runs ----------
__global__ __launch_bounds__(256) void p1_scatter_kernel(const int* __restrict__ src,
                                                         const int* __restrict__ dst,
                                                         int* __restrict__ bcur,
                                                         int* __restrict__ gpair) {
    __shared__ int h[NBKT], rb[NBKT], hc[NBKT];
    int tid = threadIdx.x;
    for (int b = tid; b < NBKT; b += 256) { h[b] = 0; hc[b] = 0; }
    __syncthreads();
    int e0 = blockIdx.x * CHUNK;
    for (int k = 0; k < CHUNK / 256; ++k) {
        int e = e0 + tid + k * 256;
        if (e < NE) atomicAdd(&h[dst[e] >> 8], 1);
    }
    __syncthreads();
    for (int b = tid; b < NBKT; b += 256)
        rb[b] = h[b] ? atomicAdd(&bcur[b], h[b]) : 0;   // reserve block-private run
    __syncthreads();
    for (int k = 0; k < CHUNK / 256; ++k) {
        int e = e0 + tid + k * 256;
        if (e < NE) {
            int d = dst[e], s = src[e];
            int b = d >> 8;
            int pos = rb[b] + atomicAdd(&hc[b], 1);
            gpair[pos] = (s << 8) | (d & 255);
        }
    }
}

// ---------- phase 2: per-bucket place -> csr (src-quartile-partitioned), seg[5], nrm ----------
// Each node's run is ordered by src quartile q = src/QSEG; seg[q][node] = start of quartile q,
// seg[4][node] = row end. Contiguous: seg[q+1][node] is the end of segment q.
__global__ __launch_bounds__(256) void p2_place_kernel(const int* __restrict__ gpair,
                                                       const int* __restrict__ bbase,
                                                       int* __restrict__ csr,
                                                       int* __restrict__ seg,
                                                       float* __restrict__ nrm) {
    __shared__ int cseg[4][256], nexcl[256], sb[4][256], pq[4][256];
    int b = blockIdx.x, tid = threadIdx.x;
    int s0 = bbase[b], s1 = bbase[b + 1];
#pragma unroll
    for (int q = 0; q < 4; ++q) { cseg[q][tid] = 0; pq[q][tid] = 0; }
    __syncthreads();
    for (int i = s0 + tid; i < s1; i += 256) {
        int p = gpair[i];
        int l = p & 255;
        int q = (p >> 8) / QSEG;
        atomicAdd(&cseg[q][l], 1);
    }
    __syncthreads();
    int v = cseg[0][tid] + cseg[1][tid] + cseg[2][tid] + cseg[3][tid];
    nexcl[tid] = v;
    __syncthreads();
    for (int off = 1; off < 256; off <<= 1) {
        int t = (tid >= off) ? nexcl[tid - off] : 0;
        __syncthreads();
        nexcl[tid] += t;
        __syncthreads();
    }
    int ex = nexcl[tid] - v;                 // exclusive within bucket
    int base = s0 + ex;
    int node = (b << 8) + tid;
    int c0 = cseg[0][tid], c1 = cseg[1][tid], c2 = cseg[2][tid];
    if (node < NN) {
        seg[0 * NNP + node] = base;
        seg[1 * NNP + node] = base + c0;
        seg[2 * NNP + node] = base + c0 + c1;
        seg[3 * NNP + node] = base + c0 + c1 + c2;
        seg[4 * NNP + node] = base + v;
        nrm[node] = rsqrtf(fmaxf((float)v, 1.0f));
    }
    sb[0][tid] = base;
    sb[1][tid] = base + c0;
    sb[2][tid] = base + c0 + c1;
    sb[3][tid] = base + c0 + c1 + c2;
    __syncthreads();
    for (int i = s0 + tid; i < s1; i += 256) {
        int p = gpair[i];
        int l = p & 255;
        int s = p >> 8;
        int q = s / QSEG;
        int pos = sb[q][l] + atomicAdd(&pq[q][l], 1);
        csr[pos] = s;                        // block-owned contiguous window
    }
}

union H4 { uint2 u; __half2 h[2]; };

// x' = fp16(x * nrm[node]); 4 floats in -> 4 halves (8 B) out per thread
__global__ void scale_x_h_kernel(const float4* __restrict__ x4, const float* __restrict__ nrm,
                                 uint2* __restrict__ xs, int total4) {
    int i = blockIdx.x * blockDim.x + threadIdx.x;
    if (i < total4) {
        float nv = nrm[i >> 4];
        float4 v = x4[i];
        H4 w;
        w.h[0] = __floats2half2_rn(v.x * nv, v.y * nv);
        w.h[1] = __floats2half2_rn(v.z * nv, v.w * nv);
        xs[i] = w.u;
    }
}

// ---------------- gather: 4 src-quartile passes, acc in registers, single launch ----------------
// Pass q touches h rows [q*QSEG,(q+1)*QSEG): 3.2 MB (IN=64) -> fits per-XCD L2.
// Blocks run passes in lockstep (all start pass 0 together) => soft temporal alignment
// without partial-RMW traffic or extra launches. seg bounds rotate: end(q) = start(q+1).
template<int IN>
__global__ __launch_bounds__(256) void gcn_gather4_kernel(
        const __half* __restrict__ h,
        const int* __restrict__ seg,          // [5][NNP]
        const int* __restrict__ csr,
        uint2* __restrict__ pAgg) {
    constexpr int MLP = 8;
    constexpr int RL  = IN / 4;        // lanes per row
    constexpr int EPI = 64 / RL;       // edges per iteration per node
    int tid = threadIdx.x;
    int wave = tid >> 6, lane = tid & 63;
    int row_slot = lane / RL;
    int f4 = lane % RL;
    int nodeBase = (blockIdx.x * 4 + wave) * MLP;
    const uint2* hp = (const uint2*)h;

    float4 acc[MLP];
#pragma unroll
    for (int i = 0; i < MLP; ++i) acc[i] = make_float4(0.f, 0.f, 0.f, 0.f);

    int cur[MLP];
#pragma unroll
    for (int i = 0; i < MLP; ++i) cur[i] = seg[nodeBase + i];

    for (int q = 0; q < 4; ++q) {
        int nxt[MLP];
#pragma unroll
        for (int i = 0; i < MLP; ++i) nxt[i] = seg[(q + 1) * NNP + nodeBase + i];
        int maxd = 0;
#pragma unroll
        for (int i = 0; i < MLP; ++i) maxd = max(maxd, nxt[i] - cur[i]);

        for (int t = 0; t < maxd; t += EPI) {
            int s[MLP]; float m[MLP];
#pragma unroll
            for (int i = 0; i < MLP; ++i) {             // batch: all csr loads
                int jj = cur[i] + t + row_slot;
                bool ok = jj < nxt[i];
                s[i] = csr[ok ? jj : 0];
                m[i] = ok ? 1.f : 0.f;
            }
            H4 v[MLP];
#pragma unroll
            for (int i = 0; i < MLP; ++i)               // batch: all row loads
                v[i].u = hp[(size_t)s[i] * RL + f4];
#pragma unroll
            for (int i = 0; i < MLP; ++i) {             // math
                float2 f01 = __half22float2(v[i].h[0]);
                float2 f23 = __half22float2(v[i].h[1]);
                acc[i].x = fmaf(m[i], f01.x, acc[i].x);
                acc[i].y = fmaf(m[i], f01.y, acc[i].y);
                acc[i].z = fmaf(m[i], f23.x, acc[i].z);
                acc[i].w = fmaf(m[i], f23.y, acc[i].w);
            }
        }
#pragma unroll
        for (int i = 0; i < MLP; ++i) cur[i] = nxt[i];
    }

#pragma unroll
    for (int i = 0; i < MLP; ++i) {
        for (int o = RL; o < 64; o <<= 1) {
            acc[i].x += __shfl_xor(acc[i].x, o);
            acc[i].y += __shfl_xor(acc[i].y, o);
            acc[i].z += __shfl_xor(acc[i].z, o);
            acc[i].w += __shfl_xor(acc[i].w, o);
        }
    }

    if (row_slot == 0) {
#pragma unroll
        for (int i = 0; i < MLP; ++i) {
            H4 w;
            w.h[0] = __floats2half2_rn(acc[i].x, acc[i].y);
            w.h[1] = __floats2half2_rn(acc[i].z, acc[i].w);
            pAgg[(size_t)(nodeBase + i) * RL + f4] = w.u;
        }
    }
}

// ---------------- apply: MFMA GEMM  out = act(nrm*(agg @ W^T) + b) ----------------
// W split hi/lo fp16 (two MFMA accums) => effective ~fp32 weights. agg fp16.
// Layouts (m89-verified): A row=lane&15, k=(lane>>4)*8+j ; B col=lane&15, k=(lane>>4)*8+j ;
// C/D col=lane&15, row=(lane>>4)*4+reg.
// Per block: 4 waves x 32 nodes = 128 nodes. Per wave: 2 A-tiles(16) x 4 out-tiles(16).
template<int IN, int ACT, bool SCALE, bool DUAL>
__global__ __launch_bounds__(256) void gcn_apply_mfma_kernel(
        const __half* __restrict__ pAgg,
        const float* __restrict__ nrm,
        const float* __restrict__ Wa, const float* __restrict__ ba,
        const float* __restrict__ Wb, const float* __restrict__ bb,
        void* __restrict__ outv, float* __restrict__ out2,
        const float* __restrict__ eps, __half* __restrict__ zbuf) {
    constexpr int KH = IN / 32;                 // K halves of 32 (2 for IN=64, 1 for IN=32)
    int tid = threadIdx.x;
    int wave = tid >> 6, lane = tid & 63;
    int col = lane & 15, kgrp = lane >> 4;

    // B fragments: B[k][c] = W[o = t*16+col][k]; hi/lo fp16 split of fp32 W.
    v8h Bhi[4][KH], Blo[4][KH];
    float bias[4];
#pragma unroll
    for (int t = 0; t < 4; ++t) {
        const float* wrow;
        if (DUAL) wrow = (t < 2) ? (Wa + (size_t)(t * 16 + col) * 64)
                                 : (Wb + (size_t)((t - 2) * 16 + col) * 64);
        else      wrow = Wa + (size_t)(t * 16 + col) * IN;
        bias[t] = DUAL ? ((t < 2) ? ba[t * 16 + col] : bb[(t - 2) * 16 + col])
                       : ba[t * 16 + col];
#pragma unroll
        for (int kh = 0; kh < KH; ++kh) {
            const float* wp = wrow + kh * 32 + kgrp * 8;
            float4 w0 = *(const float4*)(wp);
            float4 w1 = *(const float4*)(wp + 4);
            float wv[8] = {w0.x, w0.y, w0.z, w0.w, w1.x, w1.y, w1.z, w1.w};
#pragma unroll
            for (int j = 0; j < 8; ++j) {
                _Float16 hv = (_Float16)wv[j];
                Bhi[t][kh][j] = hv;
                Blo[t][kh][j] = (_Float16)(wv[j] - (float)hv);
            }
        }
    }

    int base = blockIdx.x * 128 + wave * 32;
    const _Float16* ag = (const _Float16*)pAgg;
    v4f acc[2][4];
#pragma unroll
    for (int a2 = 0; a2 < 2; ++a2)
#pragma unroll
        for (int t = 0; t < 4; ++t)
            acc[a2][t] = (v4f){0.f, 0.f, 0.f, 0.f};

#pragma unroll
    for (int a2 = 0; a2 < 2; ++a2) {
        int arow = base + a2 * 16 + col;
        if (arow > NN - 1) arow = NN - 1;               // tail guard (stores masked below)
        const _Float16* arp = ag + (size_t)arow * IN + kgrp * 8;
        v8h A0 = *(const v8h*)(arp);
        v8h A1{};
        if constexpr (KH == 2) A1 = *(const v8h*)(arp + 32);
#pragma unroll
        for (int t = 0; t < 4; ++t) {
            acc[a2][t] = __builtin_amdgcn_mfma_f32_16x16x32_f16(A0, Bhi[t][0], acc[a2][t], 0, 0, 0);
            acc[a2][t] = __builtin_amdgcn_mfma_f32_16x16x32_f16(A0, Blo[t][0], acc[a2][t], 0, 0, 0);
            if constexpr (KH == 2) {
                acc[a2][t] = __builtin_amdgcn_mfma_f32_16x16x32_f16(A1, Bhi[t][1], acc[a2][t], 0, 0, 0);
                acc[a2][t] = __builtin_amdgcn_mfma_f32_16x16x32_f16(A1, Blo[t][1], acc[a2][t], 0, 0, 0);
            }
        }
    }

    // epilogue: node = base + a2*16 + kgrp*4 + r ; o = t*16 + col
#pragma unroll
    for (int a2 = 0; a2 < 2; ++a2) {
#pragma unroll
        for (int r = 0; r < 4; ++r) {
            int node = base + a2 * 16 + kgrp * 4 + r;
            if (node >= NN) continue;
            float nv = nrm[node];
            float oa[4];
#pragma unroll
            for (int t = 0; t < 4; ++t) {
                float v = acc[a2][t][r] * nv + bias[t];
                if (ACT == 1) v = fmaxf(v, 0.f);
                if (ACT == 2) v = 1.f / (1.f + expf(-v));
                oa[t] = v;
            }
            if (DUAL) {
                float* mu_p = (float*)outv;
#pragma unroll
                for (int t = 0; t < 2; ++t) {
                    int zo = t * 16 + col;
                    float muv = oa[t], lvv = oa[t + 2];
                    mu_p[(size_t)node * 32 + zo] = muv;
                    out2[(size_t)node * 32 + zo] = lvv;
                    float e = eps[(size_t)node * 32 + zo];
                    zbuf[(size_t)node * 32 + zo] = __float2half((e * expf(0.5f * lvv) + muv) * nv);
                }
            } else if (SCALE) {
                __half* op = (__half*)outv + (size_t)node * 64 + col;
#pragma unroll
                for (int t = 0; t < 4; ++t) op[t * 16] = __float2half(oa[t] * nv);
            } else {
                float* op = (float*)outv + (size_t)node * 64 + col;
#pragma unroll
                for (int t = 0; t < 4; ++t) op[t * 16] = oa[t];
            }
        }
    }
}

extern "C" void kernel_launch(void* const* d_in, const int* in_sizes, int n_in,
                              void* d_out, int out_size, void* d_ws, size_t ws_size,
                              hipStream_t stream) {
    const float* x    = (const float*)d_in[0];
    const int*   esrc = (const int*)d_in[1];
    const int*   edst = (const int*)d_in[2];
    const float* eps  = (const float*)d_in[3];
    const float* W1  = (const float*)d_in[4];  const float* b1  = (const float*)d_in[5];
    const float* W2  = (const float*)d_in[6];  const float* b2  = (const float*)d_in[7];
    const float* W31 = (const float*)d_in[8];  const float* b31 = (const float*)d_in[9];
    const float* W32 = (const float*)d_in[10]; const float* b32 = (const float*)d_in[11];
    const float* W4  = (const float*)d_in[12]; const float* b4  = (const float*)d_in[13];
    const float* W5  = (const float*)d_in[14]; const float* b5  = (const float*)d_in[15];
    const float* W6  = (const float*)d_in[16]; const float* b6  = (const float*)d_in[17];

    float* outp  = (float*)d_out;
    float* recon = outp;                        // N*64
    float* mu    = outp + (size_t)NN * 64;      // N*32
    float* lv    = mu   + (size_t)NN * 32;      // N*32

    int* wsI       = (int*)d_ws;
    int* bcnt      = wsI;                       // 392
    int* bbase     = bcnt + 392;                // 392
    int* bcur      = bbase + 392;               // 392
    int* seg       = bcur + 392;                // 5*NNP (quartile starts + end)
    int* csr       = seg + 5 * NNP;             // NE
    float* nrm     = (float*)(csr + NE);        // NN
    __half* pAgg   = (__half*)(nrm + NN);       // NN*64 halves (12.8 MB), 16B-aligned
    __half* hA     = pAgg + (size_t)NN * 64;    // NN*64 halves
    __half* hB     = hA + (size_t)NN * 64;      // NN*64 halves
    int* gpair     = (int*)pAgg;                // aliased: dead after p2_place

    const int SB = 256;
    const int fgrid = NN / 32;                  // 3125: 4 waves x 8 nodes
    const int agrid = (NN + 127) / 128;         // 782: MFMA apply, 128 nodes/block

    // ---- CSR build: bucket counting sort (src-quartile-partitioned per node) ----
    hipMemsetAsync(bcnt, 0, 392 * sizeof(int), stream);
    p0_hist_kernel<<<NB1, 256, 0, stream>>>(edst, bcnt);
    scan_buckets_kernel<<<1, 512, 0, stream>>>(bcnt, bbase, bcur);
    p1_scatter_kernel<<<NB1, 256, 0, stream>>>(esrc, edst, bcur, gpair);
    p2_place_kernel<<<NBKT, 256, 0, stream>>>(gpair, bbase, csr, seg, nrm);

    // ---- pre-scale input to fp16 ----
    scale_x_h_kernel<<<(NN * 16 + SB - 1) / SB, SB, 0, stream>>>((const float4*)x, nrm, (uint2*)hA, NN * 16);

    uint2* pW = (uint2*)pAgg;
    const __half* pH = (const __half*)pAgg;

    // ---- layers: gather4 (single launch, 4 in-register passes) + apply (MFMA) ----
    // L1
    gcn_gather4_kernel<64><<<fgrid, 256, 0, stream>>>(hA, seg, csr, pW);
    gcn_apply_mfma_kernel<64, 1, true,  false><<<agrid, 256, 0, stream>>>(pH, nrm, W1,  b1,  nullptr, nullptr, hB,    nullptr, nullptr, nullptr);
    // L2
    gcn_gather4_kernel<64><<<fgrid, 256, 0, stream>>>(hB, seg, csr, pW);
    gcn_apply_mfma_kernel<64, 1, true,  false><<<agrid, 256, 0, stream>>>(pH, nrm, W2,  b2,  nullptr, nullptr, hA,    nullptr, nullptr, nullptr);
    // L3 dual: mu/lv -> d_out (fp32), fused z' -> hB (fp16, N*32)
    gcn_gather4_kernel<64><<<fgrid, 256, 0, stream>>>(hA, seg, csr, pW);
    gcn_apply_mfma_kernel<64, 0, false, true ><<<agrid, 256, 0, stream>>>(pH, nrm, W31, b31, W32,     b32,     mu,    lv,      eps,     hB);
    // L4 (IN=32)
    gcn_gather4_kernel<32><<<fgrid, 256, 0, stream>>>(hB, seg, csr, pW);
    gcn_apply_mfma_kernel<32, 1, true,  false><<<agrid, 256, 0, stream>>>(pH, nrm, W4,  b4,  nullptr, nullptr, hA,    nullptr, nullptr, nullptr);
    // L5
    gcn_gather4_kernel<64><<<fgrid, 256, 0, stream>>>(hA, seg, csr, pW);
    gcn_apply_mfma_kernel<64, 1, true,  false><<<agrid, 256, 0, stream>>>(pH, nrm, W5,  b5,  nullptr, nullptr, hB,    nullptr, nullptr, nullptr);
    // L6
    gcn_gather4_kernel<64><<<fgrid, 256, 0, stream>>>(hB, seg, csr, pW);
    gcn_apply_mfma_kernel<64, 2, false, false><<<agrid, 256, 0, stream>>>(pH, nrm, W6,  b6,  nullptr, nullptr, recon, nullptr, nullptr, nullptr);
}